// Round 11
// baseline (735.754 us; speedup 1.0000x reference)
//
#include <hip/hip_runtime.h>
#include <hip/hip_fp16.h>

// ---------------------------------------------------------------------------
// 3-layer GCN, reassociated:  Z_{l+1} = relu( (A_hat · Z_l) @ W_l + b_l )
// A_hat = D^-1/2 (A+I) D^-1/2. CSR gather aggregation, colnorm precomputed.
// All activations fp16 (x converted once): halves random-gather bytes.
// GEMM = split-bf16 MFMA, A staged in LDS (36KB -> 4 blocks/CU), weights read
// directly from global (256KB, L2-resident -- staging them was pure overhead).
// ---------------------------------------------------------------------------

typedef __bf16 bf16x8 __attribute__((ext_vector_type(8)));
typedef float  f32x4  __attribute__((ext_vector_type(4)));
typedef unsigned short ushort_t;
typedef unsigned int   uint_t;

__device__ __forceinline__ ushort_t f2bf(float f) {
    uint_t u = __builtin_bit_cast(uint_t, f);
    u += 0x7FFFu + ((u >> 16) & 1u);       // RNE
    return (ushort_t)(u >> 16);
}
__device__ __forceinline__ float bf2f(ushort_t h) {
    uint_t u = ((uint_t)h) << 16;
    return __builtin_bit_cast(float, u);
}
__device__ __forceinline__ float4 h4_to_f4(uint2 u) {
    __half2 a = __builtin_bit_cast(__half2, u.x);
    __half2 b = __builtin_bit_cast(__half2, u.y);
    float2 fa = __half22float2(a);
    float2 fb = __half22float2(b);
    return make_float4(fa.x, fa.y, fb.x, fb.y);
}
__device__ __forceinline__ float2 h2_to_f2(uint_t u) {
    __half2 a = __builtin_bit_cast(__half2, u);
    return __half22float2(a);
}

// ---- edge dtype detection: int64 edges have all-zero high words ------------
__global__ void k_detect(const int* __restrict__ ei, int E, int* __restrict__ flag) {
    __shared__ int nonzero;
    if (threadIdx.x == 0) nonzero = 0;
    __syncthreads();
    size_t k = (size_t)threadIdx.x * (size_t)E / 256;
    if (ei[2 * k + 1] != 0) atomicOr(&nonzero, 1);
    __syncthreads();
    if (threadIdx.x == 0) *flag = (nonzero == 0) ? 1 : 0;   // 1 => int64
}

__global__ __launch_bounds__(256) void k_convert(const int* __restrict__ ei, int E,
                                                 const int* __restrict__ flag,
                                                 int* __restrict__ src32,
                                                 int* __restrict__ dst32) {
    int is64 = *flag;
    for (int e = blockIdx.x * 256 + threadIdx.x; e < E; e += gridDim.x * 256) {
        if (is64) {
            const long long* p = (const long long*)ei;
            src32[e] = (int)p[e];
            dst32[e] = (int)p[(size_t)E + e];
        } else {
            src32[e] = ei[e];
            dst32[e] = ei[(size_t)E + e];
        }
    }
}

__global__ __launch_bounds__(256) void k_zero_int(int* __restrict__ p, int n) {
    for (int i = blockIdx.x * 256 + threadIdx.x; i < n; i += gridDim.x * 256) p[i] = 0;
}

__global__ __launch_bounds__(256) void k_count(const int* __restrict__ dst,
                                               int* __restrict__ indeg, int E) {
    for (int e = blockIdx.x * 256 + threadIdx.x; e < E; e += gridDim.x * 256)
        atomicAdd(&indeg[dst[e]], 1);
}

__global__ __launch_bounds__(256) void k_dinv(const int* __restrict__ indeg,
                                              float* __restrict__ dinv, int N) {
    int i = blockIdx.x * 256 + threadIdx.x;
    if (i < N) dinv[i] = rsqrtf(1.0f + (float)indeg[i]);   // +1 self-loop
}

// ---- exclusive scan of indeg[N] -> rowptr ----------------------------------
__global__ __launch_bounds__(256) void k_scan1(const int* __restrict__ indeg,
                                               int* __restrict__ rowptr,
                                               int* __restrict__ partials, int N) {
    __shared__ int sdata[256];
    const int b = blockIdx.x, t = threadIdx.x;
    const int base = b * 1024 + t * 4;
    int v[4], s = 0;
#pragma unroll
    for (int j = 0; j < 4; ++j) { v[j] = (base + j < N) ? indeg[base + j] : 0; s += v[j]; }
    sdata[t] = s;
    __syncthreads();
    for (int off = 1; off < 256; off <<= 1) {
        int x = (t >= off) ? sdata[t - off] : 0;
        __syncthreads();
        sdata[t] += x;
        __syncthreads();
    }
    int run = (t > 0) ? sdata[t - 1] : 0;
    if (t == 255) partials[b] = sdata[255];
#pragma unroll
    for (int j = 0; j < 4; ++j) {
        if (base + j < N) rowptr[base + j] = run;
        run += v[j];
    }
}

__global__ __launch_bounds__(256) void k_scan2(int* __restrict__ partials, int nb) {
    __shared__ int sdata[256];
    int t = threadIdx.x;
    sdata[t] = (t < nb) ? partials[t] : 0;
    __syncthreads();
    for (int off = 1; off < 256; off <<= 1) {
        int x = (t >= off) ? sdata[t - off] : 0;
        __syncthreads();
        sdata[t] += x;
        __syncthreads();
    }
    if (t < nb) partials[t] = (t > 0) ? sdata[t - 1] : 0;
}

__global__ __launch_bounds__(256) void k_scan3(int* __restrict__ rowptr,
                                               const int* __restrict__ partials,
                                               int N, int E) {
    for (int i = blockIdx.x * 256 + threadIdx.x; i < N; i += gridDim.x * 256)
        rowptr[i] += partials[i >> 10];
    if (blockIdx.x == 0 && threadIdx.x == 0) rowptr[N] = E;
}

// ---- CSR fill: colsrc + precomputed edge norm ------------------------------
__global__ __launch_bounds__(256) void k_fill(const int* __restrict__ src,
                                              const int* __restrict__ dst,
                                              const int* __restrict__ rowptr,
                                              const float* __restrict__ dinv,
                                              int* __restrict__ fillcnt,
                                              int* __restrict__ colsrc,
                                              float* __restrict__ colnorm, int E) {
    for (int e = blockIdx.x * 256 + threadIdx.x; e < E; e += gridDim.x * 256) {
        int d = dst[e], s = src[e];
        int pos = rowptr[d] + atomicAdd(&fillcnt[d], 1);
        colsrc[pos]  = s;
        colnorm[pos] = dinv[s] * dinv[d];
    }
}

// ---- weight transpose + hi/lo split: Wt[n][k] = split(W[k][n]) -------------
__global__ __launch_bounds__(256) void k_wsplit(const float* __restrict__ W,
                                                ushort_t* __restrict__ Wh,
                                                ushort_t* __restrict__ Wl,
                                                int K, int Nn) {
    int idx = blockIdx.x * 256 + threadIdx.x;
    if (idx >= K * Nn) return;
    int k = idx / Nn, n = idx - k * Nn;
    float w = W[idx];
    ushort_t h = f2bf(w);
    ushort_t l = f2bf(w - bf2f(h));
    Wh[(size_t)n * K + k] = h;
    Wl[(size_t)n * K + k] = l;
}

// ---- x (fp32) -> fp16, vectorized ------------------------------------------
__global__ __launch_bounds__(256) void k_x2h(const float* __restrict__ x,
                                             __half* __restrict__ xh, size_t n4) {
    for (size_t i = (size_t)blockIdx.x * 256 + threadIdx.x; i < n4;
         i += (size_t)gridDim.x * 256) {
        float4 v = *(const float4*)&x[i * 4];
        __half2 a = __floats2half2_rn(v.x, v.y);
        __half2 b = __floats2half2_rn(v.z, v.w);
        uint2 u;
        u.x = __builtin_bit_cast(uint_t, a);
        u.y = __builtin_bit_cast(uint_t, b);
        *(uint2*)&xh[i * 4] = u;
    }
}

// ---- aggregation (fp16 input, C cols) -> split-bf16 planes -----------------
// oh/ol[i,:] = split( dinv[i]^2 z[i,:] + sum_e colnorm[e] z[colsrc[e],:] )
// one wave per node; lane owns VE consecutive cols; 2-deep unroll.
template <int C>
__global__ __launch_bounds__(256) void k_agg_f16(const __half* __restrict__ z,
                                                 const int* __restrict__ rowptr,
                                                 const int* __restrict__ colsrc,
                                                 const float* __restrict__ colnorm,
                                                 const float* __restrict__ dinv,
                                                 ushort_t* __restrict__ oh,
                                                 ushort_t* __restrict__ ol, int N) {
    constexpr int VE = C / 64;   // 2 or 4 halves per lane
    const int node = (int)(((size_t)blockIdx.x * 256 + threadIdx.x) >> 6);
    const int lane = threadIdx.x & 63;
    if (node >= N) return;
    const float di = dinv[node];
    float a0[VE], a1[VE];
    {
        const float s2 = di * di;
        if constexpr (VE == 4) {
            float4 zv = h4_to_f4(*(const uint2*)&z[(size_t)node * C + lane * 4]);
            a0[0] = zv.x * s2; a0[1] = zv.y * s2; a0[2] = zv.z * s2; a0[3] = zv.w * s2;
            a1[0] = a1[1] = a1[2] = a1[3] = 0.f;
        } else {
            float2 zv = h2_to_f2(*(const uint_t*)&z[(size_t)node * C + lane * 2]);
            a0[0] = zv.x * s2; a0[1] = zv.y * s2;
            a1[0] = a1[1] = 0.f;
        }
    }
    const int start = rowptr[node], end = rowptr[node + 1];
    for (int base = start; base < end; base += 64) {
        const int rem = end - base;
        int sv = 0; float nv = 0.f;
        if (lane < rem) { sv = colsrc[base + lane]; nv = colnorm[base + lane]; }
        const int cnt = rem < 64 ? rem : 64;
        int jj = 0;
        for (; jj + 2 <= cnt; jj += 2) {
            int   s0 = __shfl(sv, jj),  s1 = __shfl(sv, jj + 1);
            float n0 = __shfl(nv, jj),  n1 = __shfl(nv, jj + 1);
            if constexpr (VE == 4) {
                float4 v0 = h4_to_f4(*(const uint2*)&z[(size_t)s0 * C + lane * 4]);
                float4 v1 = h4_to_f4(*(const uint2*)&z[(size_t)s1 * C + lane * 4]);
                a0[0] = fmaf(v0.x, n0, a0[0]); a0[1] = fmaf(v0.y, n0, a0[1]);
                a0[2] = fmaf(v0.z, n0, a0[2]); a0[3] = fmaf(v0.w, n0, a0[3]);
                a1[0] = fmaf(v1.x, n1, a1[0]); a1[1] = fmaf(v1.y, n1, a1[1]);
                a1[2] = fmaf(v1.z, n1, a1[2]); a1[3] = fmaf(v1.w, n1, a1[3]);
            } else {
                float2 v0 = h2_to_f2(*(const uint_t*)&z[(size_t)s0 * C + lane * 2]);
                float2 v1 = h2_to_f2(*(const uint_t*)&z[(size_t)s1 * C + lane * 2]);
                a0[0] = fmaf(v0.x, n0, a0[0]); a0[1] = fmaf(v0.y, n0, a0[1]);
                a1[0] = fmaf(v1.x, n1, a1[0]); a1[1] = fmaf(v1.y, n1, a1[1]);
            }
        }
        if (jj < cnt) {
            int   s0 = __shfl(sv, jj);
            float n0 = __shfl(nv, jj);
            if constexpr (VE == 4) {
                float4 v0 = h4_to_f4(*(const uint2*)&z[(size_t)s0 * C + lane * 4]);
                a0[0] = fmaf(v0.x, n0, a0[0]); a0[1] = fmaf(v0.y, n0, a0[1]);
                a0[2] = fmaf(v0.z, n0, a0[2]); a0[3] = fmaf(v0.w, n0, a0[3]);
            } else {
                float2 v0 = h2_to_f2(*(const uint_t*)&z[(size_t)s0 * C + lane * 2]);
                a0[0] = fmaf(v0.x, n0, a0[0]); a0[1] = fmaf(v0.y, n0, a0[1]);
            }
        }
    }
    ushort_t h[VE], l[VE];
#pragma unroll
    for (int j = 0; j < VE; ++j) {
        float a = a0[j] + a1[j];
        h[j] = f2bf(a);
        l[j] = f2bf(a - bf2f(h[j]));
    }
    size_t ob = (size_t)node * C + lane * VE;
    if constexpr (VE == 4) {
        uint2 hv, lv;
        hv.x = (uint_t)h[0] | ((uint_t)h[1] << 16);
        hv.y = (uint_t)h[2] | ((uint_t)h[3] << 16);
        lv.x = (uint_t)l[0] | ((uint_t)l[1] << 16);
        lv.y = (uint_t)l[2] | ((uint_t)l[3] << 16);
        *(uint2*)&oh[ob] = hv;
        *(uint2*)&ol[ob] = lv;
    } else {
        *(uint_t*)&oh[ob] = (uint_t)h[0] | ((uint_t)h[1] << 16);
        *(uint_t*)&ol[ob] = (uint_t)l[0] | ((uint_t)l[1] << 16);
    }
}

// ---- split-bf16 MFMA GEMM, A staged in LDS, B direct from global (L2) ------
// C[M,Nn] = relu((Ah+Al)[M,K] @ (Wh+Wl)^T_as_[Nn,K] + bias), 3-pass split.
// BM=BN=128, BK=64, 4 waves (2x2), wave tile 64x64 = 4x4 MFMA 16x16x32.
// LDS 36KB -> 4 blocks/CU; weights (<=256KB) live in L2 across the grid.
template <typename OutT>
__global__ __launch_bounds__(256, 4) void k_gemm_mfma(
    const ushort_t* __restrict__ Ah, const ushort_t* __restrict__ Al,
    const ushort_t* __restrict__ Bh, const ushort_t* __restrict__ Bl,
    const float* __restrict__ bias, OutT* __restrict__ C,
    int M, int K, int Nn) {
    __shared__ ushort_t As[2][128][72];   // [plane][m][k] pad 64->72 (bank spread)
    const int tid  = threadIdx.x;
    const int lane = tid & 63;
    const int wid  = tid >> 6;
    const int wr   = wid >> 1, wc = wid & 1;
    const int bm   = blockIdx.x * 128;
    const int bn   = blockIdx.y * 128;
    const int srow = tid >> 3;            // 0..31 (stage row base)
    const int sk8  = tid & 7;             // 16B segment within row

    f32x4 acc[4][4] = {};

    for (int kt = 0; kt < K; kt += 64) {
        __syncthreads();
#pragma unroll
        for (int j = 0; j < 4; ++j) {
            int row = srow + j * 32;
            uint4 vh = make_uint4(0, 0, 0, 0), vl = vh;
            int gr = bm + row;
            if (gr < M) {
                vh = *(const uint4*)&Ah[(size_t)gr * K + kt + sk8 * 8];
                vl = *(const uint4*)&Al[(size_t)gr * K + kt + sk8 * 8];
            }
            *(uint4*)&As[0][row][sk8 * 8] = vh;
            *(uint4*)&As[1][row][sk8 * 8] = vl;
        }
        __syncthreads();
#pragma unroll
        for (int ks = 0; ks < 2; ++ks) {
            const int acol = ks * 32 + ((lane >> 4) << 3);
            const int ar   = (wr << 6) + (lane & 15);
            bf16x8 ah[4], al[4];
#pragma unroll
            for (int t4 = 0; t4 < 4; ++t4) {
                ah[t4] = *(const bf16x8*)&As[0][ar + t4 * 16][acol];
                al[t4] = *(const bf16x8*)&As[1][ar + t4 * 16][acol];
            }
#pragma unroll
            for (int nt = 0; nt < 4; ++nt) {
                const size_t gn = (size_t)(bn + (wc << 6) + nt * 16 + (lane & 15));
                bf16x8 bh = *(const bf16x8*)&Bh[gn * K + kt + acol];
                bf16x8 bl = *(const bf16x8*)&Bl[gn * K + kt + acol];
#pragma unroll
                for (int mt = 0; mt < 4; ++mt) {
                    acc[mt][nt] = __builtin_amdgcn_mfma_f32_16x16x32_bf16(
                        ah[mt], bh, acc[mt][nt], 0, 0, 0);
                    acc[mt][nt] = __builtin_amdgcn_mfma_f32_16x16x32_bf16(
                        ah[mt], bl, acc[mt][nt], 0, 0, 0);
                    acc[mt][nt] = __builtin_amdgcn_mfma_f32_16x16x32_bf16(
                        al[mt], bh, acc[mt][nt], 0, 0, 0);
                }
            }
        }
    }

    // epilogue: D layout col=lane&15, row=(lane>>4)*4+reg
    const int col0  = bn + (wc << 6) + (lane & 15);
    const int rbase = bm + (wr << 6) + ((lane >> 4) << 2);
    float bv[4];
#pragma unroll
    for (int nt = 0; nt < 4; ++nt) bv[nt] = bias[col0 + nt * 16];
#pragma unroll
    for (int mt = 0; mt < 4; ++mt)
#pragma unroll
        for (int j = 0; j < 4; ++j) {
            int r = rbase + mt * 16 + j;
            if (r < M) {
                OutT* cp = &C[(size_t)r * Nn + col0];
#pragma unroll
                for (int nt = 0; nt < 4; ++nt) {
                    float v = fmaxf(acc[mt][nt][j] + bv[nt], 0.f);
                    if constexpr (sizeof(OutT) == 2)
                        cp[nt * 16] = __float2half_rn(v);
                    else
                        cp[nt * 16] = v;
                }
            }
        }
}

extern "C" void kernel_launch(void* const* d_in, const int* in_sizes, int n_in,
                              void* d_out, int out_size, void* d_ws, size_t ws_size,
                              hipStream_t stream) {
    const float* x  = (const float*)d_in[0];
    const int*   ei = (const int*)d_in[1];
    const float* W0 = (const float*)d_in[2];
    const float* b0 = (const float*)d_in[3];
    const float* W1 = (const float*)d_in[4];
    const float* b1 = (const float*)d_in[5];
    const float* W2 = (const float*)d_in[6];
    const float* b2 = (const float*)d_in[7];

    const int D = 128, H = 256;
    const int N = in_sizes[0] / D;
    const int E = in_sizes[1] / 2;

    char* ws = (char*)d_ws;
    auto align = [](size_t v) { return (v + 511) & ~(size_t)511; };
    size_t o = 0;
    int*      flag     = (int*)(ws + o);      o += align(sizeof(int));
    float*    dinv     = (float*)(ws + o);    o += align((size_t)N * 4);
    int*      indeg    = (int*)(ws + o);      o += align((size_t)N * 4);
    int*      fillcnt  = (int*)(ws + o);      o += align((size_t)N * 4);
    int*      rowptr   = (int*)(ws + o);      o += align(((size_t)N + 1) * 4);
    int*      partials = (int*)(ws + o);      o += align(256 * 4);
    int*      src32    = (int*)(ws + o);      o += align((size_t)E * 4);
    int*      dst32    = (int*)(ws + o);      o += align((size_t)E * 4);
    int*      colsrc   = (int*)(ws + o);      o += align((size_t)E * 4);
    float*    colnorm  = (float*)(ws + o);    o += align((size_t)E * 4);
    ushort_t* Wth      = (ushort_t*)(ws + o); o += align((size_t)H * H * 2);
    ushort_t* Wtl      = (ushort_t*)(ws + o); o += align((size_t)H * H * 2);
    ushort_t* Wth2     = (ushort_t*)(ws + o); o += align((size_t)H * H * 2);
    ushort_t* Wtl2     = (ushort_t*)(ws + o); o += align((size_t)H * H * 2);
    ushort_t* Wth3     = (ushort_t*)(ws + o); o += align((size_t)H * H * 2);
    ushort_t* Wtl3     = (ushort_t*)(ws + o); o += align((size_t)H * H * 2);
    ushort_t* Ah       = (ushort_t*)(ws + o); o += align((size_t)N * H * 2);
    ushort_t* Al       = (ushort_t*)(ws + o); o += align((size_t)N * H * 2);
    __half*   z16      = (__half*)(ws + o);   o += align((size_t)N * H * 2);
    __half*   x16      = (__half*)(ws + o);   o += align((size_t)N * D * 2);
    float*    out      = (float*)d_out;

    const int nBlkN  = (N + 255) / 256;
    const int nBlkE  = (E + 255) / 256;
    const int nbScan = (N + 1023) / 1024;

    // ---- normalization + CSR build (colnorm precomputed) ----
    k_detect<<<1, 256, 0, stream>>>(ei, E, flag);
    k_convert<<<nBlkE, 256, 0, stream>>>(ei, E, flag, src32, dst32);
    k_zero_int<<<nBlkN, 256, 0, stream>>>(indeg, N);
    k_zero_int<<<nBlkN, 256, 0, stream>>>(fillcnt, N);
    k_count<<<nBlkE, 256, 0, stream>>>(dst32, indeg, E);
    k_dinv<<<nBlkN, 256, 0, stream>>>(indeg, dinv, N);
    k_scan1<<<nbScan, 256, 0, stream>>>(indeg, rowptr, partials, N);
    k_scan2<<<1, 256, 0, stream>>>(partials, nbScan);
    k_scan3<<<nBlkN, 256, 0, stream>>>(rowptr, partials, N, E);
    k_fill<<<nBlkE, 256, 0, stream>>>(src32, dst32, rowptr, dinv, fillcnt,
                                      colsrc, colnorm, E);

    // ---- weight splits + x->fp16 (tiny; all up front) ----
    k_wsplit<<<(D * H + 255) / 256, 256, 0, stream>>>(W0, Wth, Wtl, D, H);
    k_wsplit<<<(H * H + 255) / 256, 256, 0, stream>>>(W1, Wth2, Wtl2, H, H);
    k_wsplit<<<(H * H + 255) / 256, 256, 0, stream>>>(W2, Wth3, Wtl3, H, H);
    k_x2h<<<2048, 256, 0, stream>>>(x, x16, (size_t)N * D / 4);

    const int aggBlk = (N * 64 + 255) / 256;     // one wave per node
    dim3 gemmGrid((N + 127) / 128, H / 128);

    // ---- layer 0: agg fp16 x16 (C=128) -> A planes; GEMM -> z16 ----
    k_agg_f16<128><<<aggBlk, 256, 0, stream>>>(x16, rowptr, colsrc, colnorm,
                                               dinv, Ah, Al, N);
    k_gemm_mfma<__half><<<gemmGrid, 256, 0, stream>>>(Ah, Al, Wth, Wtl, b0,
                                                      z16, N, D, H);

    // ---- layer 1: agg fp16 z16 (C=256) -> A planes; GEMM -> z16 ----
    k_agg_f16<256><<<aggBlk, 256, 0, stream>>>(z16, rowptr, colsrc, colnorm,
                                               dinv, Ah, Al, N);
    k_gemm_mfma<__half><<<gemmGrid, 256, 0, stream>>>(Ah, Al, Wth2, Wtl2, b1,
                                                      z16, N, H, H);

    // ---- layer 2: agg fp16 z16 -> A planes; GEMM -> fp32 d_out ----
    k_agg_f16<256><<<aggBlk, 256, 0, stream>>>(z16, rowptr, colsrc, colnorm,
                                               dinv, Ah, Al, N);
    k_gemm_mfma<float><<<gemmGrid, 256, 0, stream>>>(Ah, Al, Wth3, Wtl3, b2,
                                                     out, N, H, H);

    (void)n_in; (void)out_size; (void)ws_size; (void)o;
}

// Round 13
// 540.962 us; speedup vs baseline: 1.3601x; 1.3601x over previous
//
#include <hip/hip_runtime.h>
#include <hip/hip_fp16.h>

// ---------------------------------------------------------------------------
// 3-layer GCN, reassociated:  Z_{l+1} = relu( (A_hat · Z_l) @ W_l + b_l )
// A_hat = D^-1/2 (A+I) D^-1/2. CSR gather aggregation, colnorm precomputed.
// All activations fp16. GEMM: A fp16 (exact), W = Wh + Wl/2048 (both fp16,
// residual scaled to stay normal), 2x mfma_f32_16x16x32_f16 passes with dual
// accumulators -> fp32-grade weights, err ~2^-23. A+B staged in LDS (bursts:
// round-11 showed trickled B reads thrash L2 under the A stream).
// ---------------------------------------------------------------------------

typedef _Float16 f16x8 __attribute__((ext_vector_type(8)));
typedef float    f32x4 __attribute__((ext_vector_type(4)));
typedef unsigned short ushort_t;
typedef unsigned int   uint_t;

__device__ __forceinline__ float4 h4_to_f4(uint2 u) {
    __half2 a = __builtin_bit_cast(__half2, u.x);
    __half2 b = __builtin_bit_cast(__half2, u.y);
    float2 fa = __half22float2(a);
    float2 fb = __half22float2(b);
    return make_float4(fa.x, fa.y, fb.x, fb.y);
}
__device__ __forceinline__ float2 h2_to_f2(uint_t u) {
    __half2 a = __builtin_bit_cast(__half2, u);
    return __half22float2(a);
}
__device__ __forceinline__ uint_t f2_to_h2(float x, float y) {
    __half2 h = __floats2half2_rn(x, y);
    return __builtin_bit_cast(uint_t, h);
}

// ---- edge dtype detection: int64 edges have all-zero high words ------------
__global__ void k_detect(const int* __restrict__ ei, int E, int* __restrict__ flag) {
    __shared__ int nonzero;
    if (threadIdx.x == 0) nonzero = 0;
    __syncthreads();
    size_t k = (size_t)threadIdx.x * (size_t)E / 256;
    if (ei[2 * k + 1] != 0) atomicOr(&nonzero, 1);
    __syncthreads();
    if (threadIdx.x == 0) *flag = (nonzero == 0) ? 1 : 0;   // 1 => int64
}

__global__ __launch_bounds__(256) void k_convert(const int* __restrict__ ei, int E,
                                                 const int* __restrict__ flag,
                                                 int* __restrict__ src32,
                                                 int* __restrict__ dst32) {
    int is64 = *flag;
    for (int e = blockIdx.x * 256 + threadIdx.x; e < E; e += gridDim.x * 256) {
        if (is64) {
            const long long* p = (const long long*)ei;
            src32[e] = (int)p[e];
            dst32[e] = (int)p[(size_t)E + e];
        } else {
            src32[e] = ei[e];
            dst32[e] = ei[(size_t)E + e];
        }
    }
}

__global__ __launch_bounds__(256) void k_zero_int(int* __restrict__ p, int n) {
    for (int i = blockIdx.x * 256 + threadIdx.x; i < n; i += gridDim.x * 256) p[i] = 0;
}

__global__ __launch_bounds__(256) void k_count(const int* __restrict__ dst,
                                               int* __restrict__ indeg, int E) {
    for (int e = blockIdx.x * 256 + threadIdx.x; e < E; e += gridDim.x * 256)
        atomicAdd(&indeg[dst[e]], 1);
}

__global__ __launch_bounds__(256) void k_dinv(const int* __restrict__ indeg,
                                              float* __restrict__ dinv, int N) {
    int i = blockIdx.x * 256 + threadIdx.x;
    if (i < N) dinv[i] = rsqrtf(1.0f + (float)indeg[i]);   // +1 self-loop
}

// ---- exclusive scan of indeg[N] -> rowptr ----------------------------------
__global__ __launch_bounds__(256) void k_scan1(const int* __restrict__ indeg,
                                               int* __restrict__ rowptr,
                                               int* __restrict__ partials, int N) {
    __shared__ int sdata[256];
    const int b = blockIdx.x, t = threadIdx.x;
    const int base = b * 1024 + t * 4;
    int v[4], s = 0;
#pragma unroll
    for (int j = 0; j < 4; ++j) { v[j] = (base + j < N) ? indeg[base + j] : 0; s += v[j]; }
    sdata[t] = s;
    __syncthreads();
    for (int off = 1; off < 256; off <<= 1) {
        int x = (t >= off) ? sdata[t - off] : 0;
        __syncthreads();
        sdata[t] += x;
        __syncthreads();
    }
    int run = (t > 0) ? sdata[t - 1] : 0;
    if (t == 255) partials[b] = sdata[255];
#pragma unroll
    for (int j = 0; j < 4; ++j) {
        if (base + j < N) rowptr[base + j] = run;
        run += v[j];
    }
}

__global__ __launch_bounds__(256) void k_scan2(int* __restrict__ partials, int nb) {
    __shared__ int sdata[256];
    int t = threadIdx.x;
    sdata[t] = (t < nb) ? partials[t] : 0;
    __syncthreads();
    for (int off = 1; off < 256; off <<= 1) {
        int x = (t >= off) ? sdata[t - off] : 0;
        __syncthreads();
        sdata[t] += x;
        __syncthreads();
    }
    if (t < nb) partials[t] = (t > 0) ? sdata[t - 1] : 0;
}

__global__ __launch_bounds__(256) void k_scan3(int* __restrict__ rowptr,
                                               const int* __restrict__ partials,
                                               int N, int E) {
    for (int i = blockIdx.x * 256 + threadIdx.x; i < N; i += gridDim.x * 256)
        rowptr[i] += partials[i >> 10];
    if (blockIdx.x == 0 && threadIdx.x == 0) rowptr[N] = E;
}

// ---- CSR fill: colsrc + precomputed edge norm ------------------------------
__global__ __launch_bounds__(256) void k_fill(const int* __restrict__ src,
                                              const int* __restrict__ dst,
                                              const int* __restrict__ rowptr,
                                              const float* __restrict__ dinv,
                                              int* __restrict__ fillcnt,
                                              int* __restrict__ colsrc,
                                              float* __restrict__ colnorm, int E) {
    for (int e = blockIdx.x * 256 + threadIdx.x; e < E; e += gridDim.x * 256) {
        int d = dst[e], s = src[e];
        int pos = rowptr[d] + atomicAdd(&fillcnt[d], 1);
        colsrc[pos]  = s;
        colnorm[pos] = dinv[s] * dinv[d];
    }
}

// ---- weight transpose + fp16 hi/lo split (lo scaled by 2048) ---------------
// Wt[n][k]: Wh = fp16(W), Wl = fp16((W - Wh) * 2048)  => W ~ Wh + Wl/2048
__global__ __launch_bounds__(256) void k_wsplit(const float* __restrict__ W,
                                                __half* __restrict__ Wh,
                                                __half* __restrict__ Wl,
                                                int K, int Nn) {
    int idx = blockIdx.x * 256 + threadIdx.x;
    if (idx >= K * Nn) return;
    int k = idx / Nn, n = idx - k * Nn;
    float w = W[idx];
    __half h = __float2half_rn(w);
    float  r = (w - __half2float(h)) * 2048.0f;
    Wh[(size_t)n * K + k] = h;
    Wl[(size_t)n * K + k] = __float2half_rn(r);
}

// ---- x (fp32) -> fp16, vectorized ------------------------------------------
__global__ __launch_bounds__(256) void k_x2h(const float* __restrict__ x,
                                             __half* __restrict__ xh, size_t n4) {
    for (size_t i = (size_t)blockIdx.x * 256 + threadIdx.x; i < n4;
         i += (size_t)gridDim.x * 256) {
        float4 v = *(const float4*)&x[i * 4];
        uint2 u;
        u.x = f2_to_h2(v.x, v.y);
        u.y = f2_to_h2(v.z, v.w);
        *(uint2*)&xh[i * 4] = u;
    }
}

// ---- aggregation (fp16 in, C cols) -> fp16 A plane -------------------------
// A[i,:] = fp16( dinv[i]^2 z[i,:] + sum_e colnorm[e] z[colsrc[e],:] )
// one wave per node; lane owns VE consecutive cols; 2-deep unroll.
template <int C>
__global__ __launch_bounds__(256) void k_agg_f16(const __half* __restrict__ z,
                                                 const int* __restrict__ rowptr,
                                                 const int* __restrict__ colsrc,
                                                 const float* __restrict__ colnorm,
                                                 const float* __restrict__ dinv,
                                                 __half* __restrict__ outA, int N) {
    constexpr int VE = C / 64;   // 2 or 4 halves per lane
    const int node = (int)(((size_t)blockIdx.x * 256 + threadIdx.x) >> 6);
    const int lane = threadIdx.x & 63;
    if (node >= N) return;
    const float di = dinv[node];
    float a0[VE], a1[VE];
    {
        const float s2 = di * di;
        if constexpr (VE == 4) {
            float4 zv = h4_to_f4(*(const uint2*)&z[(size_t)node * C + lane * 4]);
            a0[0] = zv.x * s2; a0[1] = zv.y * s2; a0[2] = zv.z * s2; a0[3] = zv.w * s2;
            a1[0] = a1[1] = a1[2] = a1[3] = 0.f;
        } else {
            float2 zv = h2_to_f2(*(const uint_t*)&z[(size_t)node * C + lane * 2]);
            a0[0] = zv.x * s2; a0[1] = zv.y * s2;
            a1[0] = a1[1] = 0.f;
        }
    }
    const int start = rowptr[node], end = rowptr[node + 1];
    for (int base = start; base < end; base += 64) {
        const int rem = end - base;
        int sv = 0; float nv = 0.f;
        if (lane < rem) { sv = colsrc[base + lane]; nv = colnorm[base + lane]; }
        const int cnt = rem < 64 ? rem : 64;
        int jj = 0;
        for (; jj + 2 <= cnt; jj += 2) {
            int   s0 = __shfl(sv, jj),  s1 = __shfl(sv, jj + 1);
            float n0 = __shfl(nv, jj),  n1 = __shfl(nv, jj + 1);
            if constexpr (VE == 4) {
                float4 v0 = h4_to_f4(*(const uint2*)&z[(size_t)s0 * C + lane * 4]);
                float4 v1 = h4_to_f4(*(const uint2*)&z[(size_t)s1 * C + lane * 4]);
                a0[0] = fmaf(v0.x, n0, a0[0]); a0[1] = fmaf(v0.y, n0, a0[1]);
                a0[2] = fmaf(v0.z, n0, a0[2]); a0[3] = fmaf(v0.w, n0, a0[3]);
                a1[0] = fmaf(v1.x, n1, a1[0]); a1[1] = fmaf(v1.y, n1, a1[1]);
                a1[2] = fmaf(v1.z, n1, a1[2]); a1[3] = fmaf(v1.w, n1, a1[3]);
            } else {
                float2 v0 = h2_to_f2(*(const uint_t*)&z[(size_t)s0 * C + lane * 2]);
                float2 v1 = h2_to_f2(*(const uint_t*)&z[(size_t)s1 * C + lane * 2]);
                a0[0] = fmaf(v0.x, n0, a0[0]); a0[1] = fmaf(v0.y, n0, a0[1]);
                a1[0] = fmaf(v1.x, n1, a1[0]); a1[1] = fmaf(v1.y, n1, a1[1]);
            }
        }
        if (jj < cnt) {
            int   s0 = __shfl(sv, jj);
            float n0 = __shfl(nv, jj);
            if constexpr (VE == 4) {
                float4 v0 = h4_to_f4(*(const uint2*)&z[(size_t)s0 * C + lane * 4]);
                a0[0] = fmaf(v0.x, n0, a0[0]); a0[1] = fmaf(v0.y, n0, a0[1]);
                a0[2] = fmaf(v0.z, n0, a0[2]); a0[3] = fmaf(v0.w, n0, a0[3]);
            } else {
                float2 v0 = h2_to_f2(*(const uint_t*)&z[(size_t)s0 * C + lane * 2]);
                a0[0] = fmaf(v0.x, n0, a0[0]); a0[1] = fmaf(v0.y, n0, a0[1]);
            }
        }
    }
    size_t ob = (size_t)node * C + lane * VE;
    if constexpr (VE == 4) {
        uint2 u;
        u.x = f2_to_h2(a0[0] + a1[0], a0[1] + a1[1]);
        u.y = f2_to_h2(a0[2] + a1[2], a0[3] + a1[3]);
        *(uint2*)&outA[ob] = u;
    } else {
        *(uint_t*)&outA[ob] = f2_to_h2(a0[0] + a1[0], a0[1] + a1[1]);
    }
}

// ---- fp16 MFMA GEMM, 2-pass (Wh + Wl/2048), fused bias+ReLU ---------------
// C[M,Nn] = relu(A16[M,K] @ (Wh + Wl/2048)^T_as_[Nn,K] + bias)
// BM=BN=128, BK=64, 4 waves (2x2), wave tile 64x64 = 4x4 MFMA 16x16x32_f16.
// A (1 plane) + B (2 planes) staged in LDS bursts (55KB -> 2 blocks/CU).
template <typename OutT>
__global__ __launch_bounds__(256, 2) void k_gemm_mfma(
    const __half* __restrict__ A16,
    const __half* __restrict__ Bh, const __half* __restrict__ Bl,
    const float* __restrict__ bias, OutT* __restrict__ C,
    int M, int K, int Nn) {
    __shared__ ushort_t As[128][72];      // [m][k] pad 64->72 (bank spread)
    __shared__ ushort_t Bs[2][128][72];   // [plane][n][k]
    const int tid  = threadIdx.x;
    const int lane = tid & 63;
    const int wid  = tid >> 6;
    const int wr   = wid >> 1, wc = wid & 1;
    const int bm   = blockIdx.x * 128;
    const int bn   = blockIdx.y * 128;
    const int srow = tid >> 3;            // 0..31 (stage row base)
    const int sk8  = tid & 7;             // 16B segment within row

    f32x4 acch[4][4] = {};
    f32x4 accl[4][4] = {};

    for (int kt = 0; kt < K; kt += 64) {
        __syncthreads();
#pragma unroll
        for (int j = 0; j < 4; ++j) {
            int row = srow + j * 32;
            uint4 va = make_uint4(0, 0, 0, 0);
            int gr = bm + row;
            if (gr < M)
                va = *(const uint4*)&A16[(size_t)gr * K + kt + sk8 * 8];
            *(uint4*)&As[row][sk8 * 8] = va;
            uint4 wh = *(const uint4*)&Bh[(size_t)(bn + row) * K + kt + sk8 * 8];
            uint4 wl = *(const uint4*)&Bl[(size_t)(bn + row) * K + kt + sk8 * 8];
            *(uint4*)&Bs[0][row][sk8 * 8] = wh;
            *(uint4*)&Bs[1][row][sk8 * 8] = wl;
        }
        __syncthreads();
#pragma unroll
        for (int ks = 0; ks < 2; ++ks) {
            const int acol = ks * 32 + ((lane >> 4) << 3);
            const int ar   = (wr << 6) + (lane & 15);
            const int br   = (wc << 6) + (lane & 15);
            f16x8 av[4], bh[4], bl[4];
#pragma unroll
            for (int t4 = 0; t4 < 4; ++t4) {
                av[t4] = *(const f16x8*)&As[ar + t4 * 16][acol];
                bh[t4] = *(const f16x8*)&Bs[0][br + t4 * 16][acol];
                bl[t4] = *(const f16x8*)&Bs[1][br + t4 * 16][acol];
            }
#pragma unroll
            for (int mt = 0; mt < 4; ++mt)
#pragma unroll
                for (int nt = 0; nt < 4; ++nt) {
                    acch[mt][nt] = __builtin_amdgcn_mfma_f32_16x16x32_f16(
                        av[mt], bh[nt], acch[mt][nt], 0, 0, 0);
                    accl[mt][nt] = __builtin_amdgcn_mfma_f32_16x16x32_f16(
                        av[mt], bl[nt], accl[mt][nt], 0, 0, 0);
                }
        }
    }

    // epilogue: D layout col=lane&15, row=(lane>>4)*4+reg
    const float lscale = 1.0f / 2048.0f;
    const int col0  = bn + (wc << 6) + (lane & 15);
    const int rbase = bm + (wr << 6) + ((lane >> 4) << 2);
    float bv[4];
#pragma unroll
    for (int nt = 0; nt < 4; ++nt) bv[nt] = bias[col0 + nt * 16];
#pragma unroll
    for (int mt = 0; mt < 4; ++mt)
#pragma unroll
        for (int j = 0; j < 4; ++j) {
            int r = rbase + mt * 16 + j;
            if (r < M) {
                OutT* cp = &C[(size_t)r * Nn + col0];
#pragma unroll
                for (int nt = 0; nt < 4; ++nt) {
                    float v = fmaxf(fmaf(accl[mt][nt][j], lscale,
                                         acch[mt][nt][j]) + bv[nt], 0.f);
                    if constexpr (sizeof(OutT) == 2)
                        cp[nt * 16] = __float2half_rn(v);
                    else
                        cp[nt * 16] = v;
                }
            }
        }
}

extern "C" void kernel_launch(void* const* d_in, const int* in_sizes, int n_in,
                              void* d_out, int out_size, void* d_ws, size_t ws_size,
                              hipStream_t stream) {
    const float* x  = (const float*)d_in[0];
    const int*   ei = (const int*)d_in[1];
    const float* W0 = (const float*)d_in[2];
    const float* b0 = (const float*)d_in[3];
    const float* W1 = (const float*)d_in[4];
    const float* b1 = (const float*)d_in[5];
    const float* W2 = (const float*)d_in[6];
    const float* b2 = (const float*)d_in[7];

    const int D = 128, H = 256;
    const int N = in_sizes[0] / D;
    const int E = in_sizes[1] / 2;

    char* ws = (char*)d_ws;
    auto align = [](size_t v) { return (v + 511) & ~(size_t)511; };
    size_t o = 0;
    int*    flag     = (int*)(ws + o);    o += align(sizeof(int));
    float*  dinv     = (float*)(ws + o);  o += align((size_t)N * 4);
    int*    indeg    = (int*)(ws + o);    o += align((size_t)N * 4);
    int*    fillcnt  = (int*)(ws + o);    o += align((size_t)N * 4);
    int*    rowptr   = (int*)(ws + o);    o += align(((size_t)N + 1) * 4);
    int*    partials = (int*)(ws + o);    o += align(256 * 4);
    int*    src32    = (int*)(ws + o);    o += align((size_t)E * 4);
    int*    dst32    = (int*)(ws + o);    o += align((size_t)E * 4);
    int*    colsrc   = (int*)(ws + o);    o += align((size_t)E * 4);
    float*  colnorm  = (float*)(ws + o);  o += align((size_t)E * 4);
    __half* Wth      = (__half*)(ws + o); o += align((size_t)H * H * 2);
    __half* Wtl      = (__half*)(ws + o); o += align((size_t)H * H * 2);
    __half* Wth2     = (__half*)(ws + o); o += align((size_t)H * H * 2);
    __half* Wtl2     = (__half*)(ws + o); o += align((size_t)H * H * 2);
    __half* Wth3     = (__half*)(ws + o); o += align((size_t)H * H * 2);
    __half* Wtl3     = (__half*)(ws + o); o += align((size_t)H * H * 2);
    __half* A16      = (__half*)(ws + o); o += align((size_t)N * H * 2);
    __half* z16      = (__half*)(ws + o); o += align((size_t)N * H * 2);
    __half* x16      = (__half*)(ws + o); o += align((size_t)N * D * 2);
    float*  out      = (float*)d_out;

    const int nBlkN  = (N + 255) / 256;
    const int nBlkE  = (E + 255) / 256;
    const int nbScan = (N + 1023) / 1024;

    // ---- normalization + CSR build (colnorm precomputed) ----
    k_detect<<<1, 256, 0, stream>>>(ei, E, flag);
    k_convert<<<nBlkE, 256, 0, stream>>>(ei, E, flag, src32, dst32);
    k_zero_int<<<nBlkN, 256, 0, stream>>>(indeg, N);
    k_zero_int<<<nBlkN, 256, 0, stream>>>(fillcnt, N);
    k_count<<<nBlkE, 256, 0, stream>>>(dst32, indeg, E);
    k_dinv<<<nBlkN, 256, 0, stream>>>(indeg, dinv, N);
    k_scan1<<<nbScan, 256, 0, stream>>>(indeg, rowptr, partials, N);
    k_scan2<<<1, 256, 0, stream>>>(partials, nbScan);
    k_scan3<<<nBlkN, 256, 0, stream>>>(rowptr, partials, N, E);
    k_fill<<<nBlkE, 256, 0, stream>>>(src32, dst32, rowptr, dinv, fillcnt,
                                      colsrc, colnorm, E);

    // ---- weight splits + x->fp16 (tiny; all up front) ----
    k_wsplit<<<(D * H + 255) / 256, 256, 0, stream>>>(W0, Wth, Wtl, D, H);
    k_wsplit<<<(H * H + 255) / 256, 256, 0, stream>>>(W1, Wth2, Wtl2, H, H);
    k_wsplit<<<(H * H + 255) / 256, 256, 0, stream>>>(W2, Wth3, Wtl3, H, H);
    k_x2h<<<2048, 256, 0, stream>>>(x, x16, (size_t)N * D / 4);

    const int aggBlk = (N * 64 + 255) / 256;     // one wave per node
    dim3 gemmGrid((N + 127) / 128, H / 128);

    // ---- layer 0: agg x16 (C=128) -> A16; GEMM -> z16 ----
    k_agg_f16<128><<<aggBlk, 256, 0, stream>>>(x16, rowptr, colsrc, colnorm,
                                               dinv, A16, N);
    k_gemm_mfma<__half><<<gemmGrid, 256, 0, stream>>>(A16, Wth, Wtl, b0,
                                                      z16, N, D, H);

    // ---- layer 1: agg z16 (C=256) -> A16; GEMM -> z16 ----
    k_agg_f16<256><<<aggBlk, 256, 0, stream>>>(z16, rowptr, colsrc, colnorm,
                                               dinv, A16, N);
    k_gemm_mfma<__half><<<gemmGrid, 256, 0, stream>>>(A16, Wth2, Wtl2, b1,
                                                      z16, N, H, H);

    // ---- layer 2: agg z16 -> A16; GEMM -> fp32 d_out ----
    k_agg_f16<256><<<aggBlk, 256, 0, stream>>>(z16, rowptr, colsrc, colnorm,
                                               dinv, A16, N);
    k_gemm_mfma<float><<<gemmGrid, 256, 0, stream>>>(A16, Wth3, Wtl3, b2,
                                                     out, N, H, H);

    (void)n_in; (void)out_size; (void)ws_size; (void)o;
}